// Round 6
// baseline (321.502 us; speedup 1.0000x reference)
//
#include <hip/hip_runtime.h>
#include <stdint.h>

// RelationalNetwork: B=8, C=64, O=256, TE=128, GT=FP=256, A=32
// v7 structure (2 launches):
//   k_pre : W2/W3 transpose->bf16, summed:=0, cnt:=0, U/V precompute
//           (c-loop unrolled for L2-load pipelining)
//   k_fuse: v4's measured-best block (256 pairs, W2^T staged in LDS once,
//           GEMM1 M-split with A built in-reg from U/V, h2 scattered over
//           W2 space, GEMM2 N-split with W3^T from L2, colsum->atomicAdd)
//           + completion-counter tail: last 8 blocks (one per b, parallel
//           on different CUs) run f_phi inline. No k_tail launch.

#define NPAIR 32896   // 256*257/2
#define NPT   129     // ceil(32896/256): last tile has 128 valid pairs
#define TOTAL (NPT * 8)

using short8  = __attribute__((ext_vector_type(8))) short;
using float4v = __attribute__((ext_vector_type(4))) float;

__device__ __forceinline__ float asf(unsigned u) {
    union { unsigned u; float f; } c; c.u = u; return c.f;
}
__device__ __forceinline__ unsigned short f2bf(float f) {
    union { float f; unsigned u; } c; c.f = f;
    unsigned u = c.u;
    u += 0x7FFFu + ((u >> 16) & 1u);   // RNE
    return (unsigned short)(u >> 16);
}
// packed f32x2 -> bf16x2 (RNE), 1 instr for 2 elements
__device__ __forceinline__ unsigned cvtpk(float lo, float hi) {
    unsigned r;
    asm("v_cvt_pk_bf16_f32 %0, %1, %2" : "=v"(r) : "v"(lo), "v"(hi));
    return r;
}
__device__ __forceinline__ void ij_of(int p, int& i, int& j) {
    float s = sqrtf(8.0f * (float)p + 1.0f);
    i = (int)((s - 1.0f) * 0.5f);
    while ((i + 1) * (i + 2) / 2 <= p) ++i;
    while (i * (i + 1) / 2 > p) --i;
    j = p - i * (i + 1) / 2;
}
// h1 A-fragment: relu(unpack(u)+unpack(v)) packed to 8 bf16
__device__ __forceinline__ short8 buildA(uint4 uu, uint4 vv) {
    unsigned ua[4] = {uu.x, uu.y, uu.z, uu.w};
    unsigned va[4] = {vv.x, vv.y, vv.z, vv.w};
    union { unsigned u[4]; short8 s; } c;
    #pragma unroll
    for (int q = 0; q < 4; ++q) {
        float lo = asf(ua[q] << 16)         + asf(va[q] << 16);
        float hi = asf(ua[q] & 0xFFFF0000u) + asf(va[q] & 0xFFFF0000u);
        c.u[q] = cvtpk(fmaxf(lo, 0.f), fmaxf(hi, 0.f));
    }
    return c.s;
}

// ---- fused preprocessing ------------------------------------------------
// grid (33, 8): x<32 -> U/V blocks; x==32 -> zero summed/cnt + transposes
__global__ __launch_bounds__(256) void k_pre(
    const float* __restrict__ x, const float* __restrict__ code,
    const float* __restrict__ w1, const float* __restrict__ b1,
    const float* __restrict__ w2, const float* __restrict__ w3,
    unsigned short* __restrict__ ub, unsigned short* __restrict__ vb,
    unsigned short* __restrict__ w2t, unsigned short* __restrict__ w3t,
    float* __restrict__ summed, unsigned* __restrict__ cnt)
{
    const int tid = threadIdx.x;
    if (blockIdx.x < 32) {
        const int ig = blockIdx.x, b = blockIdx.y, d = tid;
        float q = b1[d];
        const float* cp = code + b * 128;
        #pragma unroll 16
        for (int t = 0; t < 128; ++t) q += cp[t] * w1[(132 + t) * 256 + d];
        float su[8], sv[8];
        #pragma unroll
        for (int k = 0; k < 8; ++k) { su[k] = q; sv[k] = 0.f; }
        const float* xp = x + (b * 64) * 256 + ig * 8;
        #pragma unroll 8
        for (int c = 0; c < 64; ++c) {
            const float wu = w1[c * 256 + d];
            const float wv = w1[(66 + c) * 256 + d];
            const float* xc = xp + c * 256;          // uniform -> scalar loads
            #pragma unroll
            for (int k = 0; k < 8; ++k) { su[k] += xc[k] * wu; sv[k] += xc[k] * wv; }
        }
        const float wyu = w1[64 * 256 + d],  wxu = w1[65 * 256 + d];
        const float wyv = w1[130 * 256 + d], wxv = w1[131 * 256 + d];
        #pragma unroll
        for (int k = 0; k < 8; ++k) {
            const int i = ig * 8 + k;
            const float yy = (float)(i >> 4) * (2.0f / 15.0f) - 1.0f;
            const float xx = (float)(i & 15) * (2.0f / 15.0f) - 1.0f;
            ub[(b * 256 + i) * 256 + d] = f2bf(su[k] + yy * wyu + xx * wxu);
            vb[(b * 256 + i) * 256 + d] = f2bf(sv[k] + yy * wyv + xx * wxv);
        }
    } else {
        __shared__ float t[64][65];
        const int y = blockIdx.y;
        summed[y * 256 + tid] = 0.f;                 // re-zeroed every replay
        if (y == 0 && tid == 0) *cnt = 0u;           // completion counter
        const int tx = tid & 63, ty = tid >> 6;
        for (int jj = 0; jj < 4; ++jj) {
            const int job = y * 4 + jj;              // 0..31
            const float* src = (job & 16) ? w3 : w2;
            unsigned short* dst = (job & 16) ? w3t : w2t;
            const int k0 = ((job >> 2) & 3) * 64, n0 = (job & 3) * 64;
            __syncthreads();
            #pragma unroll
            for (int r = ty; r < 64; r += 4) t[r][tx] = src[(k0 + r) * 256 + n0 + tx];
            __syncthreads();
            #pragma unroll
            for (int r = ty; r < 64; r += 4) dst[(n0 + r) * 256 + k0 + tx] = f2bf(t[tx][r]);
        }
    }
}

// ---- fused g_theta chain for 256 pairs + inline f_phi tail --------------
// Chunk swizzle everywhere: 16B chunk c of row r stored at chunk (c ^ (r&7)).
__global__ __launch_bounds__(512) void k_fuse(
    const unsigned short* __restrict__ ub, const unsigned short* __restrict__ vb,
    const unsigned short* __restrict__ w2t, const unsigned short* __restrict__ w3t,
    const float* __restrict__ b2, const float* __restrict__ b3,
    float* __restrict__ summed, unsigned* __restrict__ cnt,
    const float* __restrict__ fw1, const float* __restrict__ fb1,
    const float* __restrict__ fw2, const float* __restrict__ fb2,
    const float* __restrict__ fw3, const float* __restrict__ fb3,
    float* __restrict__ out)
{
    extern __shared__ unsigned short lds[];        // 128 KiB
    const int tid  = threadIdx.x;
    const int pt   = blockIdx.x, b = blockIdx.y;
    const int lane = tid & 63, w = tid >> 6;
    const int lm   = lane & 15, quad = lane >> 4;

    // ---- stage W2^T[n][k] into LDS, chunk-swizzled ----
    #pragma unroll
    for (int it = 0; it < 16; ++it) {
        const int idx = it * 512 + tid;
        const int n = idx >> 5, c = idx & 31;
        const uint4 d = *(const uint4*)(w2t + n * 256 + c * 8);
        *(uint4*)(&lds[n * 256 + ((c ^ (n & 7)) << 3)]) = d;
    }

    // ---- GEMM1 row setup (wave owns rows w*32..w*32+31) ----
    const unsigned short* up[2];
    const unsigned short* vp[2];
    #pragma unroll
    for (int mt = 0; mt < 2; ++mt) {
        const int p0 = pt * 256 + w * 32 + mt * 16 + lm;
        const int p  = p0 < NPAIR ? p0 : NPAIR - 1;
        int i, j; ij_of(p, i, j);
        up[mt] = ub + ((b * 256 + i) * 256) + quad * 8;
        vp[mt] = vb + ((b * 256 + j) * 256) + quad * 8;
    }
    const int wave_valid = (pt * 256 + w * 32) < NPAIR;
    __syncthreads();

    const float4v zero4 = {0.f, 0.f, 0.f, 0.f};

    // ---- GEMM1: h2 = relu(U_i+V_j) @ W2, A built in-reg, B from LDS ----
    float4v acc1[2][16];
    #pragma unroll
    for (int mt = 0; mt < 2; ++mt)
        #pragma unroll
        for (int nt = 0; nt < 16; ++nt) acc1[mt][nt] = zero4;
    {
        uint4 cu[2], cv[2];
        #pragma unroll
        for (int mt = 0; mt < 2; ++mt) {
            cu[mt] = *(const uint4*)(up[mt]);
            cv[mt] = *(const uint4*)(vp[mt]);
        }
        for (int ks = 0; ks < 8; ++ks) {
            uint4 nu[2], nv[2];
            if (ks < 7) {
                #pragma unroll
                for (int mt = 0; mt < 2; ++mt) {
                    nu[mt] = *(const uint4*)(up[mt] + (ks + 1) * 32);
                    nv[mt] = *(const uint4*)(vp[mt] + (ks + 1) * 32);
                }
            }
            short8 afr[2];
            #pragma unroll
            for (int mt = 0; mt < 2; ++mt) afr[mt] = buildA(cu[mt], cv[mt]);
            const int coff = ((ks * 4 + quad) ^ (lm & 7)) << 3;
            __builtin_amdgcn_s_setprio(1);
            #pragma unroll
            for (int ng = 0; ng < 4; ++ng) {
                short8 bfr[4];
                #pragma unroll
                for (int q = 0; q < 4; ++q)
                    bfr[q] = *(const short8*)(&lds[((ng * 4 + q) * 16 + lm) * 256 + coff]);
                #pragma unroll
                for (int mt = 0; mt < 2; ++mt)
                    #pragma unroll
                    for (int q = 0; q < 4; ++q)
                        acc1[mt][ng * 4 + q] = __builtin_amdgcn_mfma_f32_16x16x32_bf16(
                            afr[mt], bfr[q], acc1[mt][ng * 4 + q], 0, 0, 0);
            }
            __builtin_amdgcn_s_setprio(0);
            #pragma unroll
            for (int mt = 0; mt < 2; ++mt) { cu[mt] = nu[mt]; cv[mt] = nv[mt]; }
        }
    }
    __syncthreads();   // all waves done reading W2 region

    // ---- scatter h2 = relu(acc1+b2) into LDS tile[256][256] (swizzled);
    //      invalid rows (last tile) written as zero ----
    const float msk = wave_valid ? 1.f : 0.f;
    #pragma unroll
    for (int nt = 0; nt < 16; ++nt) {
        const float bb = b2[nt * 16 + lm];
        const int col = nt * 16 + lm;
        #pragma unroll
        for (int mt = 0; mt < 2; ++mt) {
            const int rbase = w * 32 + mt * 16 + quad * 4;
            const float v0 = fmaxf(acc1[mt][nt][0] + bb, 0.f) * msk;
            const float v1 = fmaxf(acc1[mt][nt][1] + bb, 0.f) * msk;
            const float v2 = fmaxf(acc1[mt][nt][2] + bb, 0.f) * msk;
            const float v3 = fmaxf(acc1[mt][nt][3] + bb, 0.f) * msk;
            const unsigned w01 = cvtpk(v0, v1), w23 = cvtpk(v2, v3);
            const int c0 = col >> 3, c7 = col & 7;
            lds[(rbase + 0) * 256 + (((c0 ^ ((rbase + 0) & 7)) << 3) | c7)] =
                (unsigned short)w01;
            lds[(rbase + 1) * 256 + (((c0 ^ ((rbase + 1) & 7)) << 3) | c7)] =
                (unsigned short)(w01 >> 16);
            lds[(rbase + 2) * 256 + (((c0 ^ ((rbase + 2) & 7)) << 3) | c7)] =
                (unsigned short)w23;
            lds[(rbase + 3) * 256 + (((c0 ^ ((rbase + 3) & 7)) << 3) | c7)] =
                (unsigned short)(w23 >> 16);
        }
    }
    __syncthreads();

    // ---- GEMM2: rel = h2 @ W3, N-split (wave owns cols w*32..+31),
    //      A from LDS h2 tile, B = W3^T slice from L2 (1-deep prefetch) ----
    float4v acc2[16][2];
    #pragma unroll
    for (int mt = 0; mt < 16; ++mt)
        #pragma unroll
        for (int nt = 0; nt < 2; ++nt) acc2[mt][nt] = zero4;
    {
        const unsigned short* bb3 = w3t + ((w * 32 + lm) * 256) + quad * 8;
        short8 bcur[2], bnxt[2];
        #pragma unroll
        for (int nt = 0; nt < 2; ++nt) bcur[nt] = *(const short8*)(bb3 + nt * 4096);
        for (int ks = 0; ks < 8; ++ks) {
            if (ks < 7) {
                #pragma unroll
                for (int nt = 0; nt < 2; ++nt)
                    bnxt[nt] = *(const short8*)(bb3 + nt * 4096 + (ks + 1) * 32);
            }
            __builtin_amdgcn_s_setprio(1);
            #pragma unroll
            for (int mt = 0; mt < 16; ++mt) {
                const int row = mt * 16 + lm;
                const short8 a = *(const short8*)(
                    &lds[row * 256 + (((ks * 4 + quad) ^ (row & 7)) << 3)]);
                #pragma unroll
                for (int nt = 0; nt < 2; ++nt)
                    acc2[mt][nt] = __builtin_amdgcn_mfma_f32_16x16x32_bf16(
                        a, bcur[nt], acc2[mt][nt], 0, 0, 0);
            }
            __builtin_amdgcn_s_setprio(0);
            #pragma unroll
            for (int nt = 0; nt < 2; ++nt) bcur[nt] = bnxt[nt];
        }
    }

    // ---- relu + column-sum over all 256 rows -> atomicAdd summed[b][col] ----
    #pragma unroll
    for (int nt = 0; nt < 2; ++nt) {
        const int col = w * 32 + nt * 16 + lm;
        const float bb = b3[col];
        float s = 0.f;
        #pragma unroll
        for (int mt = 0; mt < 16; ++mt)
            #pragma unroll
            for (int rg = 0; rg < 4; ++rg)
                s += fmaxf(acc2[mt][nt][rg] + bb, 0.f);
        s += __shfl_xor(s, 16);
        s += __shfl_xor(s, 32);
        if (quad == 0)
            atomicAdd(&summed[b * 256 + col], s);
    }

    // ---- completion-counter tail: last 8 blocks run f_phi (one per b) ----
    volatile int* eflag = (volatile int*)(lds + 4096);   // byte offset 8192
    __threadfence();
    __syncthreads();           // all waves issued + fenced their atomics
    if (tid == 0) {
        unsigned old = __hip_atomic_fetch_add(cnt, 1u, __ATOMIC_ACQ_REL,
                                              __HIP_MEMORY_SCOPE_AGENT);
        *eflag = (old >= TOTAL - 8) ? (int)(TOTAL - 1 - old) : -1;
    }
    __syncthreads();
    const int eb = *eflag;     // elected batch, or -1
    if (eb < 0) return;
    if (tid == 0) {
        while (__hip_atomic_load(cnt, __ATOMIC_ACQUIRE,
                                 __HIP_MEMORY_SCOPE_AGENT) < TOTAL)
            __builtin_amdgcn_s_sleep(2);
    }
    __syncthreads();

    // f_phi for batch eb (fp32), 512 threads, LDS scratch in tile region
    float* fs   = (float*)lds;       // [256]
    float* fred = fs + 256;          // [512]
    float* fact = fs + 768;          // [256]
    const int d = tid & 255, kh = tid >> 8;        // kh 0..1
    if (kh == 0)
        fs[d] = __hip_atomic_load(&summed[eb * 256 + d], __ATOMIC_RELAXED,
                                  __HIP_MEMORY_SCOPE_AGENT);
    __syncthreads();
    float p = 0.f;
    #pragma unroll 16
    for (int k = kh * 128; k < kh * 128 + 128; ++k) p += fs[k] * fw1[k * 256 + d];
    fred[kh * 256 + d] = p;
    __syncthreads();
    if (kh == 0) fact[d] = fmaxf(fred[d] + fred[256 + d] + fb1[d], 0.f);
    __syncthreads();
    p = 0.f;
    #pragma unroll 16
    for (int k = kh * 128; k < kh * 128 + 128; ++k) p += fact[k] * fw2[k * 256 + d];
    fred[kh * 256 + d] = p;
    __syncthreads();
    if (kh == 0) fs[d] = fmaxf(fred[d] + fred[256 + d] + fb2[d], 0.f);
    __syncthreads();
    const int d3 = tid & 31, g = tid >> 5;         // g 0..15
    p = 0.f;
    #pragma unroll
    for (int k = g * 16; k < g * 16 + 16; ++k) p += fs[k] * fw3[k * 32 + d3];
    fred[g * 32 + d3] = p;
    __syncthreads();
    if (tid < 32) {
        float o = fb3[tid];
        #pragma unroll
        for (int r = 0; r < 16; ++r) o += fred[r * 32 + tid];
        out[eb * 32 + tid] = o;
    }
}

extern "C" void kernel_launch(void* const* d_in, const int* in_sizes, int n_in,
                              void* d_out, int out_size, void* d_ws, size_t ws_size,
                              hipStream_t stream) {
    const float* x    = (const float*)d_in[0];
    const float* code = (const float*)d_in[1];
    const float* gw1  = (const float*)d_in[2];
    const float* gb1  = (const float*)d_in[3];
    const float* gw2  = (const float*)d_in[4];
    const float* gb2  = (const float*)d_in[5];
    const float* gw3  = (const float*)d_in[6];
    const float* gb3  = (const float*)d_in[7];
    const float* fw1  = (const float*)d_in[8];
    const float* fb1  = (const float*)d_in[9];
    const float* fw2  = (const float*)d_in[10];
    const float* fb2  = (const float*)d_in[11];
    const float* fw3  = (const float*)d_in[12];
    const float* fb3  = (const float*)d_in[13];
    float* out = (float*)d_out;

    // workspace layout (bytes), total ~2.27 MB
    char* ws = (char*)d_ws;
    unsigned short* ub  = (unsigned short*)(ws);               // 1 MiB
    unsigned short* vb  = (unsigned short*)(ws + 1048576);     // 1 MiB
    unsigned short* w2t = (unsigned short*)(ws + 2097152);     // 128 KiB
    unsigned short* w3t = (unsigned short*)(ws + 2228224);     // 128 KiB
    float* summed = (float*)(ws + 2359296);                    // 8 KiB
    unsigned* cnt = (unsigned*)(ws + 2367488);                 // 4 B

    hipLaunchKernelGGL(k_pre, dim3(33, 8), dim3(256), 0, stream,
                       x, code, gw1, gb1, gw2, gw3, ub, vb, w2t, w3t, summed, cnt);
    hipLaunchKernelGGL(k_fuse, dim3(NPT, 8), dim3(512), 131072, stream,
                       ub, vb, w2t, w3t, gb2, gb3, summed, cnt,
                       fw1, fb1, fw2, fb2, fw3, fb3, out);
}

// Round 8
// 190.929 us; speedup vs baseline: 1.6839x; 1.6839x over previous
//
#include <hip/hip_runtime.h>
#include <stdint.h>

// RelationalNetwork: B=8, C=64, O=256, TE=128, GT=FP=256, A=32
// v8 structure (3 launches) = v4 revert + 2-deep prefetch + k_pre unroll:
//   k_pre : W2/W3 transpose->bf16, summed:=0, U/V precompute (pipelined)
//   k_fuse: block = 256 pairs x full g_theta L2+L3 chain.
//           W2^T staged in LDS once; GEMM1 M-split with A built in-reg
//           from U/V (2-deep prefetch); h2 scattered to LDS (reusing W2
//           space); GEMM2 N-split with A from LDS and W3^T slices from L2
//           (2-deep prefetch); rowsum -> atomicAdd summed.
//   k_tail: f_phi on 8 blocks x 1024 threads (4-way k-split per layer)
// (Resubmission of round-6 source: round-7 bench was an infra failure,
//  not a kernel failure — identical source for a clean measurement.)

#define NPAIR 32896   // 256*257/2
#define NPT   129     // ceil(32896/256): last tile has 128 valid pairs

using short8  = __attribute__((ext_vector_type(8))) short;
using float4v = __attribute__((ext_vector_type(4))) float;

__device__ __forceinline__ float asf(unsigned u) {
    union { unsigned u; float f; } c; c.u = u; return c.f;
}
__device__ __forceinline__ unsigned short f2bf(float f) {
    union { float f; unsigned u; } c; c.f = f;
    unsigned u = c.u;
    u += 0x7FFFu + ((u >> 16) & 1u);   // RNE
    return (unsigned short)(u >> 16);
}
// packed f32x2 -> bf16x2 (RNE), 1 instr for 2 elements
__device__ __forceinline__ unsigned cvtpk(float lo, float hi) {
    unsigned r;
    asm("v_cvt_pk_bf16_f32 %0, %1, %2" : "=v"(r) : "v"(lo), "v"(hi));
    return r;
}
__device__ __forceinline__ void ij_of(int p, int& i, int& j) {
    float s = sqrtf(8.0f * (float)p + 1.0f);
    i = (int)((s - 1.0f) * 0.5f);
    while ((i + 1) * (i + 2) / 2 <= p) ++i;
    while (i * (i + 1) / 2 > p) --i;
    j = p - i * (i + 1) / 2;
}
// h1 A-fragment: relu(unpack(u)+unpack(v)) packed to 8 bf16
__device__ __forceinline__ short8 buildA(uint4 uu, uint4 vv) {
    unsigned ua[4] = {uu.x, uu.y, uu.z, uu.w};
    unsigned va[4] = {vv.x, vv.y, vv.z, vv.w};
    union { unsigned u[4]; short8 s; } c;
    #pragma unroll
    for (int q = 0; q < 4; ++q) {
        float lo = asf(ua[q] << 16)         + asf(va[q] << 16);
        float hi = asf(ua[q] & 0xFFFF0000u) + asf(va[q] & 0xFFFF0000u);
        c.u[q] = cvtpk(fmaxf(lo, 0.f), fmaxf(hi, 0.f));
    }
    return c.s;
}

// ---- fused preprocessing ------------------------------------------------
// grid (33, 8): x<32 -> U/V blocks; x==32 -> zero summed + transpose jobs
__global__ __launch_bounds__(256) void k_pre(
    const float* __restrict__ x, const float* __restrict__ code,
    const float* __restrict__ w1, const float* __restrict__ b1,
    const float* __restrict__ w2, const float* __restrict__ w3,
    unsigned short* __restrict__ ub, unsigned short* __restrict__ vb,
    unsigned short* __restrict__ w2t, unsigned short* __restrict__ w3t,
    float* __restrict__ summed)
{
    const int tid = threadIdx.x;
    if (blockIdx.x < 32) {
        const int ig = blockIdx.x, b = blockIdx.y, d = tid;
        float q = b1[d];
        const float* cp = code + b * 128;
        #pragma unroll 16
        for (int t = 0; t < 128; ++t) q += cp[t] * w1[(132 + t) * 256 + d];
        float su[8], sv[8];
        #pragma unroll
        for (int k = 0; k < 8; ++k) { su[k] = q; sv[k] = 0.f; }
        const float* xp = x + (b * 64) * 256 + ig * 8;
        #pragma unroll 8
        for (int c = 0; c < 64; ++c) {
            const float wu = w1[c * 256 + d];
            const float wv = w1[(66 + c) * 256 + d];
            const float* xc = xp + c * 256;          // uniform -> scalar loads
            #pragma unroll
            for (int k = 0; k < 8; ++k) { su[k] += xc[k] * wu; sv[k] += xc[k] * wv; }
        }
        const float wyu = w1[64 * 256 + d],  wxu = w1[65 * 256 + d];
        const float wyv = w1[130 * 256 + d], wxv = w1[131 * 256 + d];
        #pragma unroll
        for (int k = 0; k < 8; ++k) {
            const int i = ig * 8 + k;
            const float yy = (float)(i >> 4) * (2.0f / 15.0f) - 1.0f;
            const float xx = (float)(i & 15) * (2.0f / 15.0f) - 1.0f;
            ub[(b * 256 + i) * 256 + d] = f2bf(su[k] + yy * wyu + xx * wxu);
            vb[(b * 256 + i) * 256 + d] = f2bf(sv[k] + yy * wyv + xx * wxv);
        }
    } else {
        __shared__ float t[64][65];
        const int y = blockIdx.y;
        summed[y * 256 + tid] = 0.f;                 // re-zeroed every replay
        const int tx = tid & 63, ty = tid >> 6;
        for (int jj = 0; jj < 4; ++jj) {
            const int job = y * 4 + jj;              // 0..31
            const float* src = (job & 16) ? w3 : w2;
            unsigned short* dst = (job & 16) ? w3t : w2t;
            const int k0 = ((job >> 2) & 3) * 64, n0 = (job & 3) * 64;
            __syncthreads();
            #pragma unroll
            for (int r = ty; r < 64; r += 4) t[r][tx] = src[(k0 + r) * 256 + n0 + tx];
            __syncthreads();
            #pragma unroll
            for (int r = ty; r < 64; r += 4) dst[(n0 + r) * 256 + k0 + tx] = f2bf(t[tx][r]);
        }
    }
}

// ---- fused g_theta chain for 256 pairs ----------------------------------
// Chunk swizzle everywhere: 16B chunk c of row r stored at chunk (c ^ (r&7)).
__global__ __launch_bounds__(512) void k_fuse(
    const unsigned short* __restrict__ ub, const unsigned short* __restrict__ vb,
    const unsigned short* __restrict__ w2t, const unsigned short* __restrict__ w3t,
    const float* __restrict__ b2, const float* __restrict__ b3,
    float* __restrict__ summed)
{
    extern __shared__ unsigned short lds[];        // 128 KiB
    const int tid  = threadIdx.x;
    const int pt   = blockIdx.x, b = blockIdx.y;
    const int lane = tid & 63, w = tid >> 6;
    const int lm   = lane & 15, quad = lane >> 4;

    // ---- stage W2^T[n][k] into LDS, chunk-swizzled ----
    #pragma unroll
    for (int it = 0; it < 16; ++it) {
        const int idx = it * 512 + tid;
        const int n = idx >> 5, c = idx & 31;
        const uint4 d = *(const uint4*)(w2t + n * 256 + c * 8);
        *(uint4*)(&lds[n * 256 + ((c ^ (n & 7)) << 3)]) = d;
    }

    // ---- GEMM1 row setup (wave owns rows w*32..w*32+31) ----
    const unsigned short* up[2];
    const unsigned short* vp[2];
    #pragma unroll
    for (int mt = 0; mt < 2; ++mt) {
        const int p0 = pt * 256 + w * 32 + mt * 16 + lm;
        const int p  = p0 < NPAIR ? p0 : NPAIR - 1;
        int i, j; ij_of(p, i, j);
        up[mt] = ub + ((b * 256 + i) * 256) + quad * 8;
        vp[mt] = vb + ((b * 256 + j) * 256) + quad * 8;
    }
    const int wave_valid = (pt * 256 + w * 32) < NPAIR;
    __syncthreads();

    const float4v zero4 = {0.f, 0.f, 0.f, 0.f};

    // ---- GEMM1: h2 = relu(U_i+V_j) @ W2, A built in-reg (2-deep prefetch),
    //      B from LDS ----
    float4v acc1[2][16];
    #pragma unroll
    for (int mt = 0; mt < 2; ++mt)
        #pragma unroll
        for (int nt = 0; nt < 16; ++nt) acc1[mt][nt] = zero4;
    {
        uint4 cu[2][2], cv[2][2];    // [parity][mt]
        #pragma unroll
        for (int kk = 0; kk < 2; ++kk)
            #pragma unroll
            for (int mt = 0; mt < 2; ++mt) {
                cu[kk][mt] = *(const uint4*)(up[mt] + kk * 32);
                cv[kk][mt] = *(const uint4*)(vp[mt] + kk * 32);
            }
        for (int ks = 0; ks < 8; ++ks) {
            const int pr = ks & 1;
            short8 afr[2];
            #pragma unroll
            for (int mt = 0; mt < 2; ++mt) afr[mt] = buildA(cu[pr][mt], cv[pr][mt]);
            if (ks < 6) {
                #pragma unroll
                for (int mt = 0; mt < 2; ++mt) {
                    cu[pr][mt] = *(const uint4*)(up[mt] + (ks + 2) * 32);
                    cv[pr][mt] = *(const uint4*)(vp[mt] + (ks + 2) * 32);
                }
            }
            const int coff = ((ks * 4 + quad) ^ (lm & 7)) << 3;
            __builtin_amdgcn_s_setprio(1);
            #pragma unroll
            for (int ng = 0; ng < 4; ++ng) {
                short8 bfr[4];
                #pragma unroll
                for (int q = 0; q < 4; ++q)
                    bfr[q] = *(const short8*)(&lds[((ng * 4 + q) * 16 + lm) * 256 + coff]);
                #pragma unroll
                for (int mt = 0; mt < 2; ++mt)
                    #pragma unroll
                    for (int q = 0; q < 4; ++q)
                        acc1[mt][ng * 4 + q] = __builtin_amdgcn_mfma_f32_16x16x32_bf16(
                            afr[mt], bfr[q], acc1[mt][ng * 4 + q], 0, 0, 0);
            }
            __builtin_amdgcn_s_setprio(0);
        }
    }
    __syncthreads();   // all waves done reading W2 region

    // ---- hoist GEMM2 B-frags ks=0,1 (latency hidden under the scatter) --
    const unsigned short* bb3 = w3t + ((w * 32 + lm) * 256) + quad * 8;
    short8 bbuf[2][2];   // [parity][nt]
    #pragma unroll
    for (int kk = 0; kk < 2; ++kk)
        #pragma unroll
        for (int nt = 0; nt < 2; ++nt)
            bbuf[kk][nt] = *(const short8*)(bb3 + nt * 4096 + kk * 32);

    // ---- scatter h2 = relu(acc1+b2) into LDS tile[256][256] (swizzled);
    //      invalid rows (last tile) written as zero ----
    const float msk = wave_valid ? 1.f : 0.f;
    #pragma unroll
    for (int nt = 0; nt < 16; ++nt) {
        const float bb = b2[nt * 16 + lm];
        const int col = nt * 16 + lm;
        #pragma unroll
        for (int mt = 0; mt < 2; ++mt) {
            const int rbase = w * 32 + mt * 16 + quad * 4;
            const float v0 = fmaxf(acc1[mt][nt][0] + bb, 0.f) * msk;
            const float v1 = fmaxf(acc1[mt][nt][1] + bb, 0.f) * msk;
            const float v2 = fmaxf(acc1[mt][nt][2] + bb, 0.f) * msk;
            const float v3 = fmaxf(acc1[mt][nt][3] + bb, 0.f) * msk;
            const unsigned w01 = cvtpk(v0, v1), w23 = cvtpk(v2, v3);
            const int c0 = col >> 3, c7 = col & 7;
            lds[(rbase + 0) * 256 + (((c0 ^ ((rbase + 0) & 7)) << 3) | c7)] =
                (unsigned short)w01;
            lds[(rbase + 1) * 256 + (((c0 ^ ((rbase + 1) & 7)) << 3) | c7)] =
                (unsigned short)(w01 >> 16);
            lds[(rbase + 2) * 256 + (((c0 ^ ((rbase + 2) & 7)) << 3) | c7)] =
                (unsigned short)w23;
            lds[(rbase + 3) * 256 + (((c0 ^ ((rbase + 3) & 7)) << 3) | c7)] =
                (unsigned short)(w23 >> 16);
        }
    }
    __syncthreads();

    // ---- GEMM2: rel = h2 @ W3, N-split (wave owns cols w*32..+31),
    //      A from LDS h2 tile, B = W3^T slice from L2 (2-deep prefetch) ----
    float4v acc2[16][2];
    #pragma unroll
    for (int mt = 0; mt < 16; ++mt)
        #pragma unroll
        for (int nt = 0; nt < 2; ++nt) acc2[mt][nt] = zero4;
    {
        for (int ks = 0; ks < 8; ++ks) {
            const int pr = ks & 1;
            short8 bcur[2];
            #pragma unroll
            for (int nt = 0; nt < 2; ++nt) bcur[nt] = bbuf[pr][nt];
            if (ks < 6) {
                #pragma unroll
                for (int nt = 0; nt < 2; ++nt)
                    bbuf[pr][nt] = *(const short8*)(bb3 + nt * 4096 + (ks + 2) * 32);
            }
            __builtin_amdgcn_s_setprio(1);
            #pragma unroll
            for (int mt = 0; mt < 16; ++mt) {
                const int row = mt * 16 + lm;
                const short8 a = *(const short8*)(
                    &lds[row * 256 + (((ks * 4 + quad) ^ (row & 7)) << 3)]);
                #pragma unroll
                for (int nt = 0; nt < 2; ++nt)
                    acc2[mt][nt] = __builtin_amdgcn_mfma_f32_16x16x32_bf16(
                        a, bcur[nt], acc2[mt][nt], 0, 0, 0);
            }
            __builtin_amdgcn_s_setprio(0);
        }
    }

    // ---- relu + column-sum over all 256 rows -> atomicAdd summed[b][col] ----
    #pragma unroll
    for (int nt = 0; nt < 2; ++nt) {
        const int col = w * 32 + nt * 16 + lm;
        const float bb = b3[col];
        float s = 0.f;
        #pragma unroll
        for (int mt = 0; mt < 16; ++mt)
            #pragma unroll
            for (int rg = 0; rg < 4; ++rg)
                s += fmaxf(acc2[mt][nt][rg] + bb, 0.f);
        s += __shfl_xor(s, 16);
        s += __shfl_xor(s, 32);
        if (quad == 0)
            atomicAdd(&summed[b * 256 + col], s);
    }
}

// ---- f_phi (fp32), 1024 threads: 4-way k-split per 256-wide layer -------
__global__ __launch_bounds__(1024) void k_tail(
    const float* __restrict__ summed,
    const float* __restrict__ fw1, const float* __restrict__ fb1,
    const float* __restrict__ fw2, const float* __restrict__ fb2,
    const float* __restrict__ fw3, const float* __restrict__ fb3,
    float* __restrict__ out)
{
    __shared__ float s0[256], s1[256], red[1024];
    const int b = blockIdx.x, tid = threadIdx.x;
    const int d = tid & 255, kh = tid >> 8;     // kh 0..3
    if (tid < 256) s0[tid] = summed[b * 256 + tid];
    __syncthreads();
    float p = 0.f;
    #pragma unroll 16
    for (int k = kh * 64; k < kh * 64 + 64; ++k) p += s0[k] * fw1[k * 256 + d];
    red[kh * 256 + d] = p;
    __syncthreads();
    if (tid < 256)
        s1[tid] = fmaxf(red[tid] + red[256 + tid] + red[512 + tid] + red[768 + tid]
                        + fb1[tid], 0.f);
    __syncthreads();
    p = 0.f;
    #pragma unroll 16
    for (int k = kh * 64; k < kh * 64 + 64; ++k) p += s1[k] * fw2[k * 256 + d];
    red[kh * 256 + d] = p;
    __syncthreads();
    if (tid < 256)
        s0[tid] = fmaxf(red[tid] + red[256 + tid] + red[512 + tid] + red[768 + tid]
                        + fb2[tid], 0.f);
    __syncthreads();
    const int d3 = tid & 31, kh3 = tid >> 5;    // kh3 0..31
    p = 0.f;
    #pragma unroll
    for (int k = kh3 * 8; k < kh3 * 8 + 8; ++k) p += s0[k] * fw3[k * 32 + d3];
    red[kh3 * 32 + d3] = p;
    __syncthreads();
    if (tid < 32) {
        float o = fb3[tid];
        #pragma unroll 8
        for (int r = 0; r < 32; ++r) o += red[r * 32 + tid];
        out[b * 32 + tid] = o;
    }
}

extern "C" void kernel_launch(void* const* d_in, const int* in_sizes, int n_in,
                              void* d_out, int out_size, void* d_ws, size_t ws_size,
                              hipStream_t stream) {
    const float* x    = (const float*)d_in[0];
    const float* code = (const float*)d_in[1];
    const float* gw1  = (const float*)d_in[2];
    const float* gb1  = (const float*)d_in[3];
    const float* gw2  = (const float*)d_in[4];
    const float* gb2  = (const float*)d_in[5];
    const float* gw3  = (const float*)d_in[6];
    const float* gb3  = (const float*)d_in[7];
    const float* fw1  = (const float*)d_in[8];
    const float* fb1  = (const float*)d_in[9];
    const float* fw2  = (const float*)d_in[10];
    const float* fb2  = (const float*)d_in[11];
    const float* fw3  = (const float*)d_in[12];
    const float* fb3  = (const float*)d_in[13];
    float* out = (float*)d_out;

    // workspace layout (bytes), total ~2.27 MB
    char* ws = (char*)d_ws;
    unsigned short* ub  = (unsigned short*)(ws);               // 1 MiB
    unsigned short* vb  = (unsigned short*)(ws + 1048576);     // 1 MiB
    unsigned short* w2t = (unsigned short*)(ws + 2097152);     // 128 KiB
    unsigned short* w3t = (unsigned short*)(ws + 2228224);     // 128 KiB
    float* summed = (float*)(ws + 2359296);                    // 8 KiB

    hipLaunchKernelGGL(k_pre, dim3(33, 8), dim3(256), 0, stream,
                       x, code, gw1, gb1, gw2, gw3, ub, vb, w2t, w3t, summed);
    hipLaunchKernelGGL(k_fuse, dim3(NPT, 8), dim3(512), 131072, stream,
                       ub, vb, w2t, w3t, gb2, gb3, summed);
    hipLaunchKernelGGL(k_tail, dim3(8), dim3(1024), 0, stream,
                       summed, fw1, fb1, fw2, fb2, fw3, fb3, out);
}